// Round 7
// baseline (258.698 us; speedup 1.0000x reference)
//
#include <hip/hip_runtime.h>
#include <hip/hip_cooperative_groups.h>

namespace cg = cooperative_groups;

#define NN 100000
#define NE 1600000
#define HIDN 256
#define OD0 20000
#define OD1 1881
#define OD2 27000
#define OUT_TOTAL (OD0 + OD1 + OD2)
#define NB_OUT ((OUT_TOTAL + 63) / 64)

// caps (expected: nL1 ~48, nS1 ~51, nL2 ~820, nS2 ~900)
#define MAXL1 8192
#define MAXS1 112
#define MAXL2 65536
#define MAXS2 8192

#define MASKW 3200       // ceil(100000/32)=3125, padded
#define CHUNK 256

__device__ __forceinline__ float wave_sum64(float v) {
#pragma unroll
    for (int off = 32; off >= 1; off >>= 1) v += __shfl_xor(v, off, 64);
    return v;
}

__device__ __forceinline__ void insert_set(unsigned* mask, int* cnt, int cap,
                                           int* slot, int* list, int n) {
    unsigned bit = 1u << (n & 31);
    unsigned old = atomicOr(&mask[n >> 5], bit);
    if (!(old & bit)) {
        int s = atomicAdd(cnt, 1);
        if (s < cap) { slot[n] = s; list[s] = n; }
    }
}

// ============================ fallback kernels ============================

__global__ void k_init(int4* base, int n4) {
    int i = blockIdx.x * blockDim.x + threadIdx.x;
    int4 z = make_int4(0, 0, 0, 0);
    for (; i < n4; i += gridDim.x * blockDim.x) base[i] = z;
}

__global__ __launch_bounds__(256) void k_scan1(
        const int* __restrict__ erow, const int* __restrict__ ecol,
        int* __restrict__ cnts, unsigned* __restrict__ mask1,
        int* __restrict__ slot1, int* __restrict__ S1, int2* __restrict__ L1) {
    int gid = blockIdx.x * blockDim.x + threadIdx.x;
    if (gid < 3) insert_set(mask1, &cnts[1], MAXS1, slot1, S1, gid);
    for (int i = gid; i < NE / 4; i += gridDim.x * blockDim.x) {
        int4 c4 = ((const int4*)ecol)[i];
        int cs[4] = {c4.x, c4.y, c4.z, c4.w};
#pragma unroll
        for (int u = 0; u < 4; u++) {
            if (cs[u] < 3) {
                int r = erow[i * 4 + u];
                int idx = atomicAdd(&cnts[0], 1);
                if (idx < MAXL1) L1[idx] = make_int2(r, cs[u]);
                insert_set(mask1, &cnts[1], MAXS1, slot1, S1, r);
            }
        }
    }
}

__global__ __launch_bounds__(256) void k_scan2(
        const int* __restrict__ erow, const int* __restrict__ ecol,
        int* __restrict__ cnts, const unsigned* __restrict__ mask1,
        unsigned* __restrict__ mask2, int* __restrict__ slot2,
        int* __restrict__ S2, const int* __restrict__ S1, int2* __restrict__ L2) {
    int gid = blockIdx.x * blockDim.x + threadIdx.x;
    int ns1 = min(cnts[1], MAXS1);
    if (gid < ns1) insert_set(mask2, &cnts[3], MAXS2, slot2, S2, S1[gid]);
    for (int i = gid; i < NE / 4; i += gridDim.x * blockDim.x) {
        int4 c4 = ((const int4*)ecol)[i];
        int cs[4] = {c4.x, c4.y, c4.z, c4.w};
#pragma unroll
        for (int u = 0; u < 4; u++) {
            int c = cs[u];
            if (mask1[c >> 5] & (1u << (c & 31))) {
                int r = erow[i * 4 + u];
                int idx = atomicAdd(&cnts[2], 1);
                if (idx < MAXL2) L2[idx] = make_int2(r, c);
                insert_set(mask2, &cnts[3], MAXS2, slot2, S2, r);
            }
        }
    }
}

#define DX_GRID 256
__global__ __launch_bounds__(256) void k_degx0(
        const int* __restrict__ cnts, const int* __restrict__ ecol,
        const unsigned* __restrict__ mask2, const int* __restrict__ slot2,
        int* __restrict__ degc,
        const int* __restrict__ S2, const float* __restrict__ latent,
        const float* __restrict__ wq, const float* __restrict__ bq,
        const float* __restrict__ wk, const float* __restrict__ bk,
        const float* __restrict__ wv, const float* __restrict__ bv,
        const float* __restrict__ ln0w, const float* __restrict__ ln0b,
        const float* __restrict__ g1w,
        float* __restrict__ x0c, float* __restrict__ h1c) {
    __shared__ float lw[3 * 4096];
    int t = threadIdx.x, b = blockIdx.x;
    int gid = b * 256 + t;
    {
        const float4* s0 = (const float4*)wq;
        const float4* s1 = (const float4*)wk;
        const float4* s2 = (const float4*)wv;
        float4* d0 = (float4*)&lw[0];
        float4* d1 = (float4*)&lw[4096];
        float4* d2 = (float4*)&lw[8192];
        for (int i = t; i < 1024; i += 256) { d0[i] = s0[i]; d1[i] = s1[i]; d2[i] = s2[i]; }
    }
    for (int i = gid; i < NE / 4; i += DX_GRID * 256) {
        int4 c4 = ((const int4*)ecol)[i];
        int cs[4] = {c4.x, c4.y, c4.z, c4.w};
#pragma unroll
        for (int u = 0; u < 4; u++) {
            int c = cs[u];
            if (mask2[c >> 5] & (1u << (c & 31))) {
                int s = slot2[c];
                if ((unsigned)s < MAXS2) atomicAdd(&degc[s], 1);
            }
        }
    }
    __syncthreads();
    int lane = t & 63, wid = t >> 6;
    int nS2 = min(cnts[3], MAXS2);
    for (int s = b * 4 + wid; s < nS2; s += DX_GRID * 4) {
        int n = S2[s];
        float xv = latent[n * 64 + lane];
        float aq = bq[lane], ak = bk[lane], av = bv[lane];
#pragma unroll
        for (int j = 0; j < 64; j++) {
            float xj = __shfl(xv, j, 64);
            aq = fmaf(xj, lw[j * 64 + lane], aq);
            ak = fmaf(xj, lw[4096 + j * 64 + lane], ak);
            av = fmaf(xj, lw[8192 + j * 64 + lane], av);
        }
        int d = lane & 15;
        float sj[4];
#pragma unroll
        for (int j = 0; j < 4; j++) {
            float kv = __shfl(ak, (j << 4) | d, 64);
            float pp = aq * kv;
            pp += __shfl_xor(pp, 1, 64); pp += __shfl_xor(pp, 2, 64);
            pp += __shfl_xor(pp, 4, 64); pp += __shfl_xor(pp, 8, 64);
            sj[j] = pp * 0.25f;
        }
        float mx = fmaxf(fmaxf(sj[0], sj[1]), fmaxf(sj[2], sj[3]));
        float e0 = expf(sj[0] - mx), e1 = expf(sj[1] - mx);
        float e2 = expf(sj[2] - mx), e3 = expf(sj[3] - mx);
        float inv = 1.f / (e0 + e1 + e2 + e3);
        float at[4] = {e0 * inv, e1 * inv, e2 * inv, e3 * inv};
        float o = 0.f;
#pragma unroll
        for (int j = 0; j < 4; j++) {
            float vv = __shfl(av, (j << 4) | d, 64);
            o = fmaf(at[j], vv, o);
        }
        float sum = wave_sum64(o), sq = wave_sum64(o * o);
        float mean = sum * (1.f / 64.f);
        float var = sq * (1.f / 64.f) - mean * mean;
        float x0 = (o - mean) * rsqrtf(var + 1e-5f) * ln0w[lane] + ln0b[lane];
        x0c[s * 64 + lane] = x0;
        float h = 0.f;
#pragma unroll
        for (int j = 0; j < 64; j++) {
            float xj = __shfl(x0, j, 64);
            h = fmaf(xj, g1w[j * 64 + lane], h);
        }
        h1c[s * 64 + lane] = h;
    }
}

#define XA_GRID 16
#define XA_R ((MAXS1 + XA_GRID - 1) / XA_GRID)   // 7
__global__ __launch_bounds__(256) void k_x1agg(
        const int* __restrict__ cnts, const int2* __restrict__ L1,
        const int2* __restrict__ L2, const int* __restrict__ S1,
        const int* __restrict__ slot1, const int* __restrict__ slot2,
        const int* __restrict__ degc,
        const float* __restrict__ x0c, const float* __restrict__ h1c,
        const float* __restrict__ g1b, const float* __restrict__ ln1w,
        const float* __restrict__ ln1b, const float* __restrict__ g2w,
        float* __restrict__ agg2, float* __restrict__ x1c3) {
    __shared__ float s_agg[XA_R * 64];
    __shared__ float s_h2[XA_R * 64];
    __shared__ int   e_a[CHUNK];
    __shared__ int   e_c[CHUNK];
    __shared__ float e_w[CHUNK];
    int t = threadIdx.x, lane = t & 63, wid = t >> 6, b = blockIdx.x;
    int nl1 = min(cnts[0], MAXL1);
    int ns1 = min(cnts[1], MAXS1);
    int nl2 = min(cnts[2], MAXL2);
    int r0 = b * XA_R;
    int r1 = min(ns1, r0 + XA_R);
    if (r1 <= r0) return;
    for (int i = t; i < XA_R * 64; i += 256) s_agg[i] = 0.f;
    __syncthreads();
    int ntot = nl2 + ns1;
    for (int e0 = 0; e0 < ntot; e0 += CHUNK) {
        int cn = min(CHUNK, ntot - e0);
        if (t < cn) {
            int e = e0 + t;
            int r, c;
            if (e < nl2) { int2 rc = L2[e]; r = rc.x; c = rc.y; }
            else { r = c = S1[e - nl2]; }
            int sc1 = slot1[c];
            int a = -1, bl = 0; float w = 0.f;
            if (sc1 >= r0 && sc1 < r1) {
                int sr2 = slot2[r], sc2 = slot2[c];
                if ((unsigned)sr2 < MAXS2 && (unsigned)sc2 < MAXS2) {
                    w = rsqrtf((float)(degc[sr2] + 1)) * rsqrtf((float)(degc[sc2] + 1));
                    a = sr2; bl = sc1 - r0;
                }
            }
            e_a[t] = a; e_c[t] = bl; e_w[t] = w;
        }
        __syncthreads();
        for (int base = wid * 8; base < cn; base += 32) {
            float v[8]; int bb[8];
#pragma unroll
            for (int u = 0; u < 8; u++) {
                int e = base + u;
                int a = (e < cn) ? e_a[e] : -1;
                bb[u] = (a >= 0) ? e_c[e] : -1;
                v[u] = (a >= 0) ? h1c[a * 64 + lane] * e_w[e] : 0.f;
            }
#pragma unroll
            for (int u = 0; u < 8; u++)
                if (bb[u] >= 0) atomicAdd(&s_agg[bb[u] * 64 + lane], v[u]);
        }
        __syncthreads();
    }
    for (int s = r0 + wid; s < r1; s += 4) {
        int n = S1[s];
        int s2 = slot2[n];
        float v = x0c[s2 * 64 + lane] + s_agg[(s - r0) * 64 + lane] + g1b[lane];
        float sum = wave_sum64(v), sq = wave_sum64(v * v);
        float mean = sum * (1.f / 64.f);
        float var = sq * (1.f / 64.f) - mean * mean;
        float x1 = (v - mean) * rsqrtf(var + 1e-5f) * ln1w[lane] + ln1b[lane];
        if (n < 3) x1c3[n * 64 + lane] = x1;
        float h = 0.f;
#pragma unroll
        for (int j = 0; j < 64; j++) {
            float xj = __shfl(x1, j, 64);
            h = fmaf(xj, g2w[j * 64 + lane], h);
        }
        s_h2[(s - r0) * 64 + lane] = h;
    }
    __syncthreads();
    int ntot2 = nl1 + 3;
    for (int f0 = 0; f0 < ntot2; f0 += CHUNK) {
        int fn = min(CHUNK, ntot2 - f0);
        if (t < fn) {
            int e = f0 + t;
            int r, c;
            if (e < nl1) { int2 rc = L1[e]; r = rc.x; c = rc.y; }
            else { r = c = e - nl1; }
            int sr1 = slot1[r];
            int a = -1; float w = 0.f;
            if (sr1 >= r0 && sr1 < r1) {
                int sr2 = slot2[r], sc2 = slot2[c];
                if ((unsigned)sr2 < MAXS2 && (unsigned)sc2 < MAXS2) {
                    w = rsqrtf((float)(degc[sr2] + 1)) * rsqrtf((float)(degc[sc2] + 1));
                    a = sr1 - r0;
                }
            }
            e_a[t] = a; e_c[t] = c; e_w[t] = w;
        }
        __syncthreads();
        for (int f = wid; f < fn; f += 4) {
            int a = e_a[f];
            if (a < 0) continue;
            atomicAdd(&agg2[e_c[f] * 64 + lane], s_h2[a * 64 + lane] * e_w[f]);
        }
        __syncthreads();
    }
}

__global__ __launch_bounds__(256) void k_out2(
        const float* __restrict__ x1c3, const float* __restrict__ agg2,
        const float* __restrict__ g2b, const float* __restrict__ ln2w,
        const float* __restrict__ ln2b,
        const float* __restrict__ w10, const float* __restrict__ b10,
        const float* __restrict__ w11, const float* __restrict__ b11,
        const float* __restrict__ w12, const float* __restrict__ b12,
        const float* __restrict__ w20, const float* __restrict__ b20,
        const float* __restrict__ w21, const float* __restrict__ b21,
        const float* __restrict__ w22, const float* __restrict__ b22,
        float* __restrict__ out) {
    __shared__ float s_x2[192];
    __shared__ float s_hg[768];
    __shared__ float part[256];
    int t = threadIdx.x, lane = t & 63, wid = t >> 6;
    if (wid < 3) {
        float v = x1c3[wid * 64 + lane] + agg2[wid * 64 + lane] + g2b[lane];
        float sum = wave_sum64(v), sq = wave_sum64(v * v);
        float mean = sum * (1.f / 64.f);
        float var = sq * (1.f / 64.f) - mean * mean;
        s_x2[wid * 64 + lane] = (v - mean) * rsqrtf(var + 1e-5f) * ln2w[lane] + ln2b[lane];
    }
    __syncthreads();
    {
        const float* W1[3] = {w10, w11, w12};
        const float* B1[3] = {b10, b11, b12};
#pragma unroll
        for (int gi = 0; gi < 3; gi++) {
            float acc = B1[gi][t];
#pragma unroll
            for (int j = 0; j < 64; j++) acc = fmaf(s_x2[gi * 64 + j], W1[gi][j * 256 + t], acc);
            s_hg[gi * 256 + t] = fmaxf(acc, 0.f);
        }
    }
    __syncthreads();
    int o = blockIdx.x * 64 + lane;
    int gi = -1, jj = 0, od = 1;
    const float* w2 = w20;
    if (o < OD0)                 { gi = 0; jj = o;             od = OD0; w2 = w20; }
    else if (o < OD0 + OD1)      { gi = 1; jj = o - OD0;       od = OD1; w2 = w21; }
    else if (o < OUT_TOTAL)      { gi = 2; jj = o - OD0 - OD1; od = OD2; w2 = w22; }
    float acc = 0.f;
    if (gi >= 0) {
        const float* h = &s_hg[gi * 256 + wid * 64];
        const float* wp = &w2[(size_t)(wid * 64) * od + jj];
#pragma unroll 16
        for (int k = 0; k < 64; k++) acc = fmaf(h[k], wp[(size_t)k * od], acc);
    }
    part[t] = acc;
    __syncthreads();
    if (t < 64 && gi >= 0) {
        float r = part[t] + part[t + 64] + part[t + 128] + part[t + 192];
        const float* b2 = (gi == 0) ? b20 : (gi == 1) ? b21 : b22;
        out[o] = r + b2[jj];
    }
}

// ============================ cooperative mega ============================

struct MP {
    const float* latent; const int* erow; const int* ecol;
    const float *wq, *bq, *wk, *bk, *wv, *bv, *ln0w, *ln0b;
    const float *g1w, *g1b, *ln1w, *ln1b, *g2w, *g2b, *ln2w, *ln2b;
    const float *w10, *b10, *w11, *b11, *w12, *b12;
    const float *w20, *b20, *w21, *b21, *w22, *b22;
    int* cnts; unsigned* mask1; unsigned* mask2; int* degc;
    int* slot1; int* slot2; int2* L1; int* S1; int2* L2; int* S2;
    float* x0c; float* h1c; float* agg2; float* x1c3;
    float* out; int zero_n4;
};

#define MGRID 256
#define MNTH  (MGRID * 256)

__global__ __launch_bounds__(256) void mega(MP p) {
    cg::grid_group g = cg::this_grid();
    __shared__ float s_row[64];
    __shared__ float s_h2[64];
    __shared__ int   e_a[CHUNK];
    __shared__ int   e_c[CHUNK];
    __shared__ float e_w[CHUNK];
    __shared__ float s_x2[192];
    __shared__ float s_hg[768];
    __shared__ float part[256];
    const int t = threadIdx.x, b = blockIdx.x;
    const int gid = b * 256 + t, lane = t & 63, wid = t >> 6, wvid = gid >> 6;

    // P0: zero the [cnts|mask1|mask2|degc|agg2] region
    {
        int4 z = make_int4(0, 0, 0, 0);
        int4* base = (int4*)p.cnts;
        for (int i = gid; i < p.zero_n4; i += MNTH) base[i] = z;
    }
    g.sync();
    // P1: scan1 -> L1, S1
    {
        if (gid < 3) insert_set(p.mask1, &p.cnts[1], MAXS1, p.slot1, p.S1, gid);
        for (int i = gid; i < NE / 4; i += MNTH) {
            int4 c4 = ((const int4*)p.ecol)[i];
            int cs[4] = {c4.x, c4.y, c4.z, c4.w};
#pragma unroll
            for (int u = 0; u < 4; u++) {
                if (cs[u] < 3) {
                    int r = p.erow[i * 4 + u];
                    int idx = atomicAdd(&p.cnts[0], 1);
                    if (idx < MAXL1) p.L1[idx] = make_int2(r, cs[u]);
                    insert_set(p.mask1, &p.cnts[1], MAXS1, p.slot1, p.S1, r);
                }
            }
        }
    }
    g.sync();
    // P2: scan2 -> L2, S2
    {
        int ns1 = min(p.cnts[1], MAXS1);
        if (gid < ns1) insert_set(p.mask2, &p.cnts[3], MAXS2, p.slot2, p.S2, p.S1[gid]);
        for (int i = gid; i < NE / 4; i += MNTH) {
            int4 c4 = ((const int4*)p.ecol)[i];
            int cs[4] = {c4.x, c4.y, c4.z, c4.w};
#pragma unroll
            for (int u = 0; u < 4; u++) {
                int c = cs[u];
                if (p.mask1[c >> 5] & (1u << (c & 31))) {
                    int r = p.erow[i * 4 + u];
                    int idx = atomicAdd(&p.cnts[2], 1);
                    if (idx < MAXL2) p.L2[idx] = make_int2(r, c);
                    insert_set(p.mask2, &p.cnts[3], MAXS2, p.slot2, p.S2, r);
                }
            }
        }
    }
    g.sync();
    // P3: degree slice + x0h1
    {
        for (int i = gid; i < NE / 4; i += MNTH) {
            int4 c4 = ((const int4*)p.ecol)[i];
            int cs[4] = {c4.x, c4.y, c4.z, c4.w};
#pragma unroll
            for (int u = 0; u < 4; u++) {
                int c = cs[u];
                if (p.mask2[c >> 5] & (1u << (c & 31))) {
                    int s = p.slot2[c];
                    if ((unsigned)s < MAXS2) atomicAdd(&p.degc[s], 1);
                }
            }
        }
        int nS2 = min(p.cnts[3], MAXS2);
        for (int s = wvid; s < nS2; s += MGRID * 4) {
            int n = p.S2[s];
            float xv = p.latent[n * 64 + lane];
            float aq = p.bq[lane], ak = p.bk[lane], av = p.bv[lane];
#pragma unroll
            for (int j = 0; j < 64; j++) {
                float xj = __shfl(xv, j, 64);
                aq = fmaf(xj, p.wq[j * 64 + lane], aq);
                ak = fmaf(xj, p.wk[j * 64 + lane], ak);
                av = fmaf(xj, p.wv[j * 64 + lane], av);
            }
            int d = lane & 15;
            float sj[4];
#pragma unroll
            for (int j = 0; j < 4; j++) {
                float kv = __shfl(ak, (j << 4) | d, 64);
                float pp = aq * kv;
                pp += __shfl_xor(pp, 1, 64); pp += __shfl_xor(pp, 2, 64);
                pp += __shfl_xor(pp, 4, 64); pp += __shfl_xor(pp, 8, 64);
                sj[j] = pp * 0.25f;
            }
            float mx = fmaxf(fmaxf(sj[0], sj[1]), fmaxf(sj[2], sj[3]));
            float e0 = expf(sj[0] - mx), e1 = expf(sj[1] - mx);
            float e2 = expf(sj[2] - mx), e3 = expf(sj[3] - mx);
            float inv = 1.f / (e0 + e1 + e2 + e3);
            float at[4] = {e0 * inv, e1 * inv, e2 * inv, e3 * inv};
            float o = 0.f;
#pragma unroll
            for (int j = 0; j < 4; j++) {
                float vv = __shfl(av, (j << 4) | d, 64);
                o = fmaf(at[j], vv, o);
            }
            float sum = wave_sum64(o), sq = wave_sum64(o * o);
            float mean = sum * (1.f / 64.f);
            float var = sq * (1.f / 64.f) - mean * mean;
            float x0 = (o - mean) * rsqrtf(var + 1e-5f) * p.ln0w[lane] + p.ln0b[lane];
            p.x0c[s * 64 + lane] = x0;
            float h = 0.f;
#pragma unroll
            for (int j = 0; j < 64; j++) {
                float xj = __shfl(x0, j, 64);
                h = fmaf(xj, p.g1w[j * 64 + lane], h);
            }
            p.h1c[s * 64 + lane] = h;
        }
    }
    g.sync();
    // P4: block b owns S1-row b -> agg1(row), x1, h2, agg2 contributions
    {
        int nl1 = min(p.cnts[0], MAXL1);
        int ns1 = min(p.cnts[1], MAXS1);
        int nl2 = min(p.cnts[2], MAXL2);
        bool active = (b < ns1);
        if (t < 64) s_row[t] = 0.f;
        __syncthreads();
        int ntot = nl2 + ns1;
        for (int e0 = 0; e0 < ntot; e0 += CHUNK) {
            int cn = min(CHUNK, ntot - e0);
            if (t < cn) {
                int e = e0 + t;
                int r, c;
                if (e < nl2) { int2 rc = p.L2[e]; r = rc.x; c = rc.y; }
                else { r = c = p.S1[e - nl2]; }
                int a = -1; float w = 0.f;
                int sc1 = p.slot1[c];
                if (active && sc1 == b) {
                    int sr2 = p.slot2[r], sc2 = p.slot2[c];
                    if ((unsigned)sr2 < MAXS2 && (unsigned)sc2 < MAXS2) {
                        w = rsqrtf((float)(p.degc[sr2] + 1)) * rsqrtf((float)(p.degc[sc2] + 1));
                        a = sr2;
                    }
                }
                e_a[t] = a; e_w[t] = w;
            }
            __syncthreads();
            for (int base = wid * 8; base < cn; base += 32) {
                float v[8]; int ok[8];
#pragma unroll
                for (int u = 0; u < 8; u++) {
                    int e = base + u;
                    int a = (e < cn) ? e_a[e] : -1;
                    ok[u] = (a >= 0);
                    v[u] = (a >= 0) ? p.h1c[a * 64 + lane] * e_w[e] : 0.f;
                }
#pragma unroll
                for (int u = 0; u < 8; u++)
                    if (ok[u]) atomicAdd(&s_row[lane], v[u]);
            }
            __syncthreads();
        }
        if (active && wid == 0) {
            int n = p.S1[b];
            int s2 = p.slot2[n];
            float v = p.x0c[s2 * 64 + lane] + s_row[lane] + p.g1b[lane];
            float sum = wave_sum64(v), sq = wave_sum64(v * v);
            float mean = sum * (1.f / 64.f);
            float var = sq * (1.f / 64.f) - mean * mean;
            float x1 = (v - mean) * rsqrtf(var + 1e-5f) * p.ln1w[lane] + p.ln1b[lane];
            if (n < 3) p.x1c3[n * 64 + lane] = x1;
            float h = 0.f;
#pragma unroll
            for (int j = 0; j < 64; j++) {
                float xj = __shfl(x1, j, 64);
                h = fmaf(xj, p.g2w[j * 64 + lane], h);
            }
            s_h2[lane] = h;
        }
        __syncthreads();
        int ntot2 = nl1 + 3;
        for (int f0 = 0; f0 < ntot2; f0 += CHUNK) {
            int fn = min(CHUNK, ntot2 - f0);
            if (t < fn) {
                int e = f0 + t;
                int r, c;
                if (e < nl1) { int2 rc = p.L1[e]; r = rc.x; c = rc.y; }
                else { r = c = e - nl1; }
                int a = -1; float w = 0.f;
                int sr1 = p.slot1[r];
                if (active && sr1 == b) {
                    int sr2 = p.slot2[r], sc2 = p.slot2[c];
                    if ((unsigned)sr2 < MAXS2 && (unsigned)sc2 < MAXS2) {
                        w = rsqrtf((float)(p.degc[sr2] + 1)) * rsqrtf((float)(p.degc[sc2] + 1));
                        a = 0;
                    }
                }
                e_a[t] = a; e_c[t] = c; e_w[t] = w;
            }
            __syncthreads();
            for (int f = wid; f < fn; f += 4) {
                if (e_a[f] < 0) continue;
                atomicAdd(&p.agg2[e_c[f] * 64 + lane], s_h2[lane] * e_w[f]);
            }
            __syncthreads();
        }
    }
    g.sync();
    // P5: x2 + hg per block, then out slices
    {
        if (wid < 3) {
            float v = p.x1c3[wid * 64 + lane] + p.agg2[wid * 64 + lane] + p.g2b[lane];
            float sum = wave_sum64(v), sq = wave_sum64(v * v);
            float mean = sum * (1.f / 64.f);
            float var = sq * (1.f / 64.f) - mean * mean;
            s_x2[wid * 64 + lane] = (v - mean) * rsqrtf(var + 1e-5f) * p.ln2w[lane] + p.ln2b[lane];
        }
        __syncthreads();
        {
            const float* W1[3] = {p.w10, p.w11, p.w12};
            const float* B1[3] = {p.b10, p.b11, p.b12};
#pragma unroll
            for (int gi = 0; gi < 3; gi++) {
                float acc = B1[gi][t];
#pragma unroll
                for (int j = 0; j < 64; j++) acc = fmaf(s_x2[gi * 64 + j], W1[gi][j * 256 + t], acc);
                s_hg[gi * 256 + t] = fmaxf(acc, 0.f);
            }
        }
        __syncthreads();
        for (int vb = b; vb < NB_OUT; vb += MGRID) {
            int o = vb * 64 + lane;
            int gi = -1, jj = 0, od = 1;
            const float* w2 = p.w20;
            if (o < OD0)                 { gi = 0; jj = o;             od = OD0; w2 = p.w20; }
            else if (o < OD0 + OD1)      { gi = 1; jj = o - OD0;       od = OD1; w2 = p.w21; }
            else if (o < OUT_TOTAL)      { gi = 2; jj = o - OD0 - OD1; od = OD2; w2 = p.w22; }
            float acc = 0.f;
            if (gi >= 0) {
                const float* h = &s_hg[gi * 256 + wid * 64];
                const float* wp = &w2[(size_t)(wid * 64) * od + jj];
#pragma unroll 16
                for (int k = 0; k < 64; k++) acc = fmaf(h[k], wp[(size_t)k * od], acc);
            }
            part[t] = acc;
            __syncthreads();
            if (t < 64 && gi >= 0) {
                float r = part[t] + part[t + 64] + part[t + 128] + part[t + 192];
                const float* b2 = (gi == 0) ? p.b20 : (gi == 1) ? p.b21 : p.b22;
                p.out[o] = r + b2[jj];
            }
            __syncthreads();
        }
    }
}

extern "C" void kernel_launch(void* const* d_in, const int* in_sizes, int n_in,
                              void* d_out, int out_size, void* d_ws, size_t ws_size,
                              hipStream_t stream) {
    (void)in_sizes; (void)n_in; (void)out_size; (void)ws_size;
    const float* latent = (const float*)d_in[0];
    const int*   edges  = (const int*)d_in[1];

    char* ptr = (char*)d_ws;
    auto alloc = [&](size_t bytes) { char* r = ptr; ptr += (bytes + 255) & ~(size_t)255; return r; };
    int*      cnts  = (int*)alloc(64 * 4);
    unsigned* mask1 = (unsigned*)alloc(MASKW * 4);
    unsigned* mask2 = (unsigned*)alloc(MASKW * 4);
    int*      degc  = (int*)alloc((size_t)MAXS2 * 4);
    float*    agg2  = (float*)alloc(192 * 4);
    char*     zero_end = ptr;
    int*      slot1 = (int*)alloc((size_t)NN * 4);
    int*      slot2 = (int*)alloc((size_t)NN * 4);
    int2*     L1    = (int2*)alloc((size_t)MAXL1 * 8);
    int*      S1    = (int*)alloc((size_t)MAXS1 * 4);
    int2*     L2    = (int2*)alloc((size_t)MAXL2 * 8);
    int*      S2    = (int*)alloc((size_t)MAXS2 * 4);
    float*    x0c   = (float*)alloc((size_t)MAXS2 * 64 * 4);
    float*    h1c   = (float*)alloc((size_t)MAXS2 * 64 * 4);
    float*    x1c3  = (float*)alloc(192 * 4);

    const int* erow = edges;
    const int* ecol = edges + NE;
    int zero_n4 = (int)((zero_end - (char*)cnts) / 16);

    MP mp;
    mp.latent = latent; mp.erow = erow; mp.ecol = ecol;
    mp.wq = (const float*)d_in[2];  mp.bq = (const float*)d_in[3];
    mp.wk = (const float*)d_in[4];  mp.bk = (const float*)d_in[5];
    mp.wv = (const float*)d_in[6];  mp.bv = (const float*)d_in[7];
    mp.ln0w = (const float*)d_in[8]; mp.ln0b = (const float*)d_in[9];
    mp.g1w = (const float*)d_in[10]; mp.g1b = (const float*)d_in[11];
    mp.ln1w = (const float*)d_in[12]; mp.ln1b = (const float*)d_in[13];
    mp.g2w = (const float*)d_in[14]; mp.g2b = (const float*)d_in[15];
    mp.ln2w = (const float*)d_in[16]; mp.ln2b = (const float*)d_in[17];
    mp.w10 = (const float*)d_in[18]; mp.b10 = (const float*)d_in[19];
    mp.w20 = (const float*)d_in[20]; mp.b20 = (const float*)d_in[21];
    mp.w11 = (const float*)d_in[22]; mp.b11 = (const float*)d_in[23];
    mp.w21 = (const float*)d_in[24]; mp.b21 = (const float*)d_in[25];
    mp.w12 = (const float*)d_in[26]; mp.b12 = (const float*)d_in[27];
    mp.w22 = (const float*)d_in[28]; mp.b22 = (const float*)d_in[29];
    mp.cnts = cnts; mp.mask1 = mask1; mp.mask2 = mask2; mp.degc = degc;
    mp.slot1 = slot1; mp.slot2 = slot2; mp.L1 = L1; mp.S1 = S1; mp.L2 = L2; mp.S2 = S2;
    mp.x0c = x0c; mp.h1c = h1c; mp.agg2 = agg2; mp.x1c3 = x1c3;
    mp.out = (float*)d_out; mp.zero_n4 = zero_n4;

    void* kargs[] = { &mp };
    hipError_t ce = hipLaunchCooperativeKernel((const void*)mega, dim3(MGRID), dim3(256),
                                               kargs, 0, stream);
    if (ce != hipSuccess) {
        const int SCAN_GRID = (NE / 4 + 255) / 256;
        k_init<<<16, 256, 0, stream>>>((int4*)cnts, zero_n4);
        k_scan1<<<SCAN_GRID, 256, 0, stream>>>(erow, ecol, cnts, mask1, slot1, S1, L1);
        k_scan2<<<SCAN_GRID, 256, 0, stream>>>(erow, ecol, cnts, mask1, mask2, slot2, S2, S1, L2);
        k_degx0<<<DX_GRID, 256, 0, stream>>>(cnts, ecol, mask2, slot2, degc, S2, latent,
                                             mp.wq, mp.bq, mp.wk, mp.bk, mp.wv, mp.bv,
                                             mp.ln0w, mp.ln0b, mp.g1w, x0c, h1c);
        k_x1agg<<<XA_GRID, 256, 0, stream>>>(cnts, L1, L2, S1, slot1, slot2, degc, x0c, h1c,
                                             mp.g1b, mp.ln1w, mp.ln1b, mp.g2w, agg2, x1c3);
        k_out2<<<NB_OUT, 256, 0, stream>>>(x1c3, agg2, mp.g2b, mp.ln2w, mp.ln2b,
                                           mp.w10, mp.b10, mp.w11, mp.b11, mp.w12, mp.b12,
                                           mp.w20, mp.b20, mp.w21, mp.b21, mp.w22, mp.b22,
                                           (float*)d_out);
    }
}

// Round 8
// 79.060 us; speedup vs baseline: 3.2722x; 3.2722x over previous
//
#include <hip/hip_runtime.h>

#define NN 100000
#define NE 1600000
#define HIDN 256
#define OD0 20000
#define OD1 1881
#define OD2 27000
#define OUT_TOTAL (OD0 + OD1 + OD2)
#define NB_OUT ((OUT_TOTAL + 63) / 64)

// caps (expected: nL1 ~48, nS1 ~51, nL2 ~820, nS2 ~900)
#define MAXL1 8192
#define MAXS1 112
#define MAXL2 65536
#define MAXS2 8192

#define MASKW 3200       // ceil(100000/32)=3125, padded
#define XB_LIST 1024     // per-row match-list cap in k_x1agg

__device__ __forceinline__ float wave_sum64(float v) {
#pragma unroll
    for (int off = 32; off >= 1; off >>= 1) v += __shfl_xor(v, off, 64);
    return v;
}

__device__ __forceinline__ void insert_set(unsigned* mask, int* cnt, int cap,
                                           int* slot, int* list, int n) {
    unsigned bit = 1u << (n & 31);
    unsigned old = atomicOr(&mask[n >> 5], bit);
    if (!(old & bit)) {
        int s = atomicAdd(cnt, 1);
        if (s < cap) { slot[n] = s; list[s] = n; }
    }
}

// ---- 1: zero [cnts | mask1 | mask2 | degc | agg2] (contiguous, int4)
__global__ void k_init(int4* base, int n4) {
    int i = blockIdx.x * blockDim.x + threadIdx.x;
    int4 z = make_int4(0, 0, 0, 0);
    for (; i < n4; i += gridDim.x * blockDim.x) base[i] = z;
}

// ---- 2: collect edges with col<3 -> L1; build S1 = {0,1,2} U rows(L1) inline
__global__ __launch_bounds__(256) void k_scan1(
        const int* __restrict__ erow, const int* __restrict__ ecol,
        int* __restrict__ cnts, unsigned* __restrict__ mask1,
        int* __restrict__ slot1, int* __restrict__ S1, int2* __restrict__ L1) {
    int gid = blockIdx.x * blockDim.x + threadIdx.x;
    if (gid < 3) insert_set(mask1, &cnts[1], MAXS1, slot1, S1, gid);
    for (int i = gid; i < NE / 4; i += gridDim.x * blockDim.x) {
        int4 c4 = ((const int4*)ecol)[i];
        int cs[4] = {c4.x, c4.y, c4.z, c4.w};
#pragma unroll
        for (int u = 0; u < 4; u++) {
            if (cs[u] < 3) {
                int r = erow[i * 4 + u];
                int idx = atomicAdd(&cnts[0], 1);
                if (idx < MAXL1) L1[idx] = make_int2(r, cs[u]);
                insert_set(mask1, &cnts[1], MAXS1, slot1, S1, r);
            }
        }
    }
}

// ---- 3: collect edges with col in S1 -> L2; build S2 = rows(L2) U S1 inline
__global__ __launch_bounds__(256) void k_scan2(
        const int* __restrict__ erow, const int* __restrict__ ecol,
        int* __restrict__ cnts, const unsigned* __restrict__ mask1,
        unsigned* __restrict__ mask2, int* __restrict__ slot2,
        int* __restrict__ S2, const int* __restrict__ S1, int2* __restrict__ L2) {
    int gid = blockIdx.x * blockDim.x + threadIdx.x;
    int ns1 = min(cnts[1], MAXS1);
    if (gid < ns1) insert_set(mask2, &cnts[3], MAXS2, slot2, S2, S1[gid]);
    for (int i = gid; i < NE / 4; i += gridDim.x * blockDim.x) {
        int4 c4 = ((const int4*)ecol)[i];
        int cs[4] = {c4.x, c4.y, c4.z, c4.w};
#pragma unroll
        for (int u = 0; u < 4; u++) {
            int c = cs[u];
            if (mask1[c >> 5] & (1u << (c & 31))) {
                int r = erow[i * 4 + u];
                int idx = atomicAdd(&cnts[2], 1);
                if (idx < MAXL2) L2[idx] = make_int2(r, c);
                insert_set(mask2, &cnts[3], MAXS2, slot2, S2, r);
            }
        }
    }
}

// ---- 4: degree scan (S2 members only) + attention/LN0/h1 over S2, fused
#define DX_GRID 256
__global__ __launch_bounds__(256) void k_degx0(
        const int* __restrict__ cnts, const int* __restrict__ ecol,
        const unsigned* __restrict__ mask2, const int* __restrict__ slot2,
        int* __restrict__ degc,
        const int* __restrict__ S2, const float* __restrict__ latent,
        const float* __restrict__ wq, const float* __restrict__ bq,
        const float* __restrict__ wk, const float* __restrict__ bk,
        const float* __restrict__ wv, const float* __restrict__ bv,
        const float* __restrict__ ln0w, const float* __restrict__ ln0b,
        const float* __restrict__ g1w,
        float* __restrict__ x0c, float* __restrict__ h1c) {
    __shared__ float lw[3 * 4096];
    int t = threadIdx.x, b = blockIdx.x;
    int gid = b * 256 + t;
    {
        const float4* s0 = (const float4*)wq;
        const float4* s1 = (const float4*)wk;
        const float4* s2 = (const float4*)wv;
        float4* d0 = (float4*)&lw[0];
        float4* d1 = (float4*)&lw[4096];
        float4* d2 = (float4*)&lw[8192];
        for (int i = t; i < 1024; i += 256) { d0[i] = s0[i]; d1[i] = s1[i]; d2[i] = s2[i]; }
    }
    for (int i = gid; i < NE / 4; i += DX_GRID * 256) {
        int4 c4 = ((const int4*)ecol)[i];
        int cs[4] = {c4.x, c4.y, c4.z, c4.w};
#pragma unroll
        for (int u = 0; u < 4; u++) {
            int c = cs[u];
            if (mask2[c >> 5] & (1u << (c & 31))) {
                int s = slot2[c];
                if ((unsigned)s < MAXS2) atomicAdd(&degc[s], 1);
            }
        }
    }
    __syncthreads();
    int lane = t & 63, wid = t >> 6;
    int nS2 = min(cnts[3], MAXS2);
    for (int s = b * 4 + wid; s < nS2; s += DX_GRID * 4) {
        int n = S2[s];
        float xv = latent[n * 64 + lane];
        float aq = bq[lane], ak = bk[lane], av = bv[lane];
#pragma unroll
        for (int j = 0; j < 64; j++) {
            float xj = __shfl(xv, j, 64);
            aq = fmaf(xj, lw[j * 64 + lane], aq);
            ak = fmaf(xj, lw[4096 + j * 64 + lane], ak);
            av = fmaf(xj, lw[8192 + j * 64 + lane], av);
        }
        int d = lane & 15;
        float sj[4];
#pragma unroll
        for (int j = 0; j < 4; j++) {
            float kv = __shfl(ak, (j << 4) | d, 64);
            float pp = aq * kv;
            pp += __shfl_xor(pp, 1, 64); pp += __shfl_xor(pp, 2, 64);
            pp += __shfl_xor(pp, 4, 64); pp += __shfl_xor(pp, 8, 64);
            sj[j] = pp * 0.25f;
        }
        float mx = fmaxf(fmaxf(sj[0], sj[1]), fmaxf(sj[2], sj[3]));
        float e0 = expf(sj[0] - mx), e1 = expf(sj[1] - mx);
        float e2 = expf(sj[2] - mx), e3 = expf(sj[3] - mx);
        float inv = 1.f / (e0 + e1 + e2 + e3);
        float at[4] = {e0 * inv, e1 * inv, e2 * inv, e3 * inv};
        float o = 0.f;
#pragma unroll
        for (int j = 0; j < 4; j++) {
            float vv = __shfl(av, (j << 4) | d, 64);
            o = fmaf(at[j], vv, o);
        }
        float sum = wave_sum64(o), sq = wave_sum64(o * o);
        float mean = sum * (1.f / 64.f);
        float var = sq * (1.f / 64.f) - mean * mean;
        float x0 = (o - mean) * rsqrtf(var + 1e-5f) * ln0w[lane] + ln0b[lane];
        x0c[s * 64 + lane] = x0;
        float h = 0.f;
#pragma unroll
        for (int j = 0; j < 64; j++) {
            float xj = __shfl(x0, j, 64);
            h = fmaf(xj, g1w[j * 64 + lane], h);
        }
        h1c[s * 64 + lane] = h;
    }
}

// ---- 5: one block per S1 row: compact match list -> parallel gather ->
//          x1 -> h2 -> ballot-driven agg2 contributions (global atomics)
__global__ __launch_bounds__(256) void k_x1agg(
        const int* __restrict__ cnts, const int2* __restrict__ L1,
        const int2* __restrict__ L2, const int* __restrict__ S1,
        const int* __restrict__ slot1, const int* __restrict__ slot2,
        const int* __restrict__ degc,
        const float* __restrict__ x0c, const float* __restrict__ h1c,
        const float* __restrict__ g1b, const float* __restrict__ ln1w,
        const float* __restrict__ ln1b, const float* __restrict__ g2w,
        float* __restrict__ agg2, float* __restrict__ x1c3) {
    __shared__ int   s_cnt;
    __shared__ int   s_ea[XB_LIST];
    __shared__ float s_ew[XB_LIST];
    __shared__ float s_part[4][64];
    int t = threadIdx.x, lane = t & 63, wid = t >> 6, b = blockIdx.x;
    int nl1 = min(cnts[0], MAXL1);
    int ns1 = min(cnts[1], MAXS1);
    int nl2 = min(cnts[2], MAXL2);
    if (b >= ns1) return;
    if (t == 0) s_cnt = 0;
    s_part[wid][lane] = 0.f;
    __syncthreads();
    int n = S1[b];                   // this block's node
    int sc2 = slot2[n];              // its S2 slot (valid: S1 subset of S2)
    float dc = rsqrtf((float)(degc[sc2] + 1));
    // resolve: thread-parallel scan of L2 + S1 self-loops, compact matches
    int ntot = nl2 + ns1;
    for (int e = t; e < ntot; e += 256) {
        int r; bool match;
        if (e < nl2) { int2 rc = L2[e]; r = rc.x; match = (slot1[rc.y] == b); }
        else         { r = S1[e - nl2]; match = (e - nl2 == b); }   // self loop
        if (match) {
            int a = slot2[r];
            if ((unsigned)a < MAXS2) {
                float w = rsqrtf((float)(degc[a] + 1)) * dc;
                int m = atomicAdd(&s_cnt, 1);
                if (m < XB_LIST) { s_ea[m] = a; s_ew[m] = w; }
            }
        }
    }
    __syncthreads();
    // accumulate: 4 waves, independent coalesced 256B gathers, wave-private partials
    int cm = min(s_cnt, XB_LIST);
    for (int m = wid; m < cm; m += 4)
        s_part[wid][lane] += h1c[s_ea[m] * 64 + lane] * s_ew[m];
    __syncthreads();
    if (wid == 0) {
        float agg = s_part[0][lane] + s_part[1][lane] + s_part[2][lane] + s_part[3][lane];
        float v = x0c[sc2 * 64 + lane] + agg + g1b[lane];
        float sum = wave_sum64(v), sq = wave_sum64(v * v);
        float mean = sum * (1.f / 64.f);
        float var = sq * (1.f / 64.f) - mean * mean;
        float x1 = (v - mean) * rsqrtf(var + 1e-5f) * ln1w[lane] + ln1b[lane];
        if (n < 3) x1c3[n * 64 + lane] = x1;
        // h2 = x1 @ gcn2_w (row-local)
        float h = 0.f;
#pragma unroll
        for (int j = 0; j < 64; j++) {
            float xj = __shfl(x1, j, 64);
            h = fmaf(xj, g2w[j * 64 + lane], h);
        }
        // agg2 contributions: edges in L1 (+{0,1,2} self-loops) whose row == n
        int ntot2 = nl1 + 3;
        for (int e0 = 0; e0 < ntot2; e0 += 64) {
            int e = e0 + lane;
            int match = 0, cc = 0; float wgt = 0.f;
            if (e < ntot2) {
                int r, c;
                if (e < nl1) { int2 rc = L1[e]; r = rc.x; c = rc.y; }
                else { r = c = e - nl1; }   // self loops for 0,1,2
                if (slot1[r] == b) {
                    int sr2 = slot2[r], scc2 = slot2[c];
                    if ((unsigned)sr2 < MAXS2 && (unsigned)scc2 < MAXS2) {
                        wgt = rsqrtf((float)(degc[sr2] + 1)) * rsqrtf((float)(degc[scc2] + 1));
                        match = 1; cc = c;
                    }
                }
            }
            unsigned long long msk = __ballot(match);
            while (msk) {
                int j = __ffsll((unsigned long long)msk) - 1;
                msk &= msk - 1;
                int cj = __shfl(cc, j, 64);
                float wj = __shfl(wgt, j, 64);
                atomicAdd(&agg2[cj * 64 + lane], h * wj);
            }
        }
    }
}

// ---- 6: x2+hg redundant per block, then 64-col GEMV slice
__global__ __launch_bounds__(256) void k_out2(
        const float* __restrict__ x1c3, const float* __restrict__ agg2,
        const float* __restrict__ g2b, const float* __restrict__ ln2w,
        const float* __restrict__ ln2b,
        const float* __restrict__ w10, const float* __restrict__ b10,
        const float* __restrict__ w11, const float* __restrict__ b11,
        const float* __restrict__ w12, const float* __restrict__ b12,
        const float* __restrict__ w20, const float* __restrict__ b20,
        const float* __restrict__ w21, const float* __restrict__ b21,
        const float* __restrict__ w22, const float* __restrict__ b22,
        float* __restrict__ out) {
    __shared__ float s_x2[192];
    __shared__ float s_hg[768];
    __shared__ float part[256];
    int t = threadIdx.x, lane = t & 63, wid = t >> 6;
    if (wid < 3) {
        float v = x1c3[wid * 64 + lane] + agg2[wid * 64 + lane] + g2b[lane];
        float sum = wave_sum64(v), sq = wave_sum64(v * v);
        float mean = sum * (1.f / 64.f);
        float var = sq * (1.f / 64.f) - mean * mean;
        s_x2[wid * 64 + lane] = (v - mean) * rsqrtf(var + 1e-5f) * ln2w[lane] + ln2b[lane];
    }
    __syncthreads();
    {
        const float* W1[3] = {w10, w11, w12};
        const float* B1[3] = {b10, b11, b12};
#pragma unroll
        for (int gi = 0; gi < 3; gi++) {
            float acc = B1[gi][t];
#pragma unroll
            for (int j = 0; j < 64; j++) acc = fmaf(s_x2[gi * 64 + j], W1[gi][j * 256 + t], acc);
            s_hg[gi * 256 + t] = fmaxf(acc, 0.f);
        }
    }
    __syncthreads();
    int o = blockIdx.x * 64 + lane;
    int gi = -1, jj = 0, od = 1;
    const float* w2 = w20;
    if (o < OD0)                 { gi = 0; jj = o;             od = OD0; w2 = w20; }
    else if (o < OD0 + OD1)      { gi = 1; jj = o - OD0;       od = OD1; w2 = w21; }
    else if (o < OUT_TOTAL)      { gi = 2; jj = o - OD0 - OD1; od = OD2; w2 = w22; }
    float acc = 0.f;
    if (gi >= 0) {
        const float* h = &s_hg[gi * 256 + wid * 64];
        const float* wp = &w2[(size_t)(wid * 64) * od + jj];
#pragma unroll 16
        for (int k = 0; k < 64; k++) acc = fmaf(h[k], wp[(size_t)k * od], acc);
    }
    part[t] = acc;
    __syncthreads();
    if (t < 64 && gi >= 0) {
        float r = part[t] + part[t + 64] + part[t + 128] + part[t + 192];
        const float* b2 = (gi == 0) ? b20 : (gi == 1) ? b21 : b22;
        out[o] = r + b2[jj];
    }
}

extern "C" void kernel_launch(void* const* d_in, const int* in_sizes, int n_in,
                              void* d_out, int out_size, void* d_ws, size_t ws_size,
                              hipStream_t stream) {
    (void)in_sizes; (void)n_in; (void)out_size; (void)ws_size;
    const float* latent = (const float*)d_in[0];
    const int*   edges  = (const int*)d_in[1];
    const float* wq  = (const float*)d_in[2];
    const float* bq  = (const float*)d_in[3];
    const float* wk  = (const float*)d_in[4];
    const float* bk  = (const float*)d_in[5];
    const float* wv  = (const float*)d_in[6];
    const float* bv  = (const float*)d_in[7];
    const float* ln0w = (const float*)d_in[8];
    const float* ln0b = (const float*)d_in[9];
    const float* g1w  = (const float*)d_in[10];
    const float* g1b  = (const float*)d_in[11];
    const float* ln1w = (const float*)d_in[12];
    const float* ln1b = (const float*)d_in[13];
    const float* g2w  = (const float*)d_in[14];
    const float* g2b  = (const float*)d_in[15];
    const float* ln2w = (const float*)d_in[16];
    const float* ln2b = (const float*)d_in[17];
    const float* gw1_0 = (const float*)d_in[18];
    const float* gb1_0 = (const float*)d_in[19];
    const float* gw2_0 = (const float*)d_in[20];
    const float* gb2_0 = (const float*)d_in[21];
    const float* gw1_1 = (const float*)d_in[22];
    const float* gb1_1 = (const float*)d_in[23];
    const float* gw2_1 = (const float*)d_in[24];
    const float* gb2_1 = (const float*)d_in[25];
    const float* gw1_2 = (const float*)d_in[26];
    const float* gb1_2 = (const float*)d_in[27];
    const float* gw2_2 = (const float*)d_in[28];
    const float* gb2_2 = (const float*)d_in[29];

    // workspace carve: [cnts|mask1|mask2|degc|agg2] = zero region
    char* ptr = (char*)d_ws;
    auto alloc = [&](size_t bytes) { char* r = ptr; ptr += (bytes + 255) & ~(size_t)255; return r; };
    int*      cnts  = (int*)alloc(64 * 4);        // [0]=nL1 [1]=nS1 [2]=nL2 [3]=nS2
    unsigned* mask1 = (unsigned*)alloc(MASKW * 4);
    unsigned* mask2 = (unsigned*)alloc(MASKW * 4);
    int*      degc  = (int*)alloc((size_t)MAXS2 * 4);
    float*    agg2  = (float*)alloc(192 * 4);
    char*     zero_end = ptr;
    int*      slot1 = (int*)alloc((size_t)NN * 4);   // valid only where mask1 bit set
    int*      slot2 = (int*)alloc((size_t)NN * 4);   // valid only where mask2 bit set
    int2*     L1    = (int2*)alloc((size_t)MAXL1 * 8);
    int*      S1    = (int*)alloc((size_t)MAXS1 * 4);
    int2*     L2    = (int2*)alloc((size_t)MAXL2 * 8);
    int*      S2    = (int*)alloc((size_t)MAXS2 * 4);
    float*    x0c   = (float*)alloc((size_t)MAXS2 * 64 * 4);
    float*    h1c   = (float*)alloc((size_t)MAXS2 * 64 * 4);
    float*    x1c3  = (float*)alloc(192 * 4);

    const int* erow = edges;
    const int* ecol = edges + NE;
    int zero_n4 = (int)((zero_end - (char*)cnts) / 16);

    const int SCAN_GRID = (NE / 4 + 255) / 256;
    k_init<<<16, 256, 0, stream>>>((int4*)cnts, zero_n4);
    k_scan1<<<SCAN_GRID, 256, 0, stream>>>(erow, ecol, cnts, mask1, slot1, S1, L1);
    k_scan2<<<SCAN_GRID, 256, 0, stream>>>(erow, ecol, cnts, mask1, mask2, slot2, S2, S1, L2);
    k_degx0<<<DX_GRID, 256, 0, stream>>>(cnts, ecol, mask2, slot2, degc, S2, latent,
                                         wq, bq, wk, bk, wv, bv, ln0w, ln0b, g1w, x0c, h1c);
    k_x1agg<<<MAXS1, 256, 0, stream>>>(cnts, L1, L2, S1, slot1, slot2, degc, x0c, h1c,
                                       g1b, ln1w, ln1b, g2w, agg2, x1c3);
    k_out2<<<NB_OUT, 256, 0, stream>>>(x1c3, agg2, g2b, ln2w, ln2b,
                                       gw1_0, gb1_0, gw1_1, gb1_1, gw1_2, gb1_2,
                                       gw2_0, gb2_0, gw2_1, gb2_1, gw2_2, gb2_2,
                                       (float*)d_out);
}